// Round 12
// baseline (209.845 us; speedup 1.0000x reference)
//
#include <hip/hip_runtime.h>

// ---------------------------------------------------------------------------
// CausalSelfAttention forward on MI355X (gfx950).
// B=4, T=2048, C=1024, H=16, hs=64.
// Pipeline: [cvt x->bf16, transpose W's] -> QKV GEMM (256x256, 4-phase,
//           per-wave 128x64, VGPR-capped 256) -> flash attention -> proj.
// Workspace layout (bytes):
//   xb    @ 0         : 8192x1024 bf16           (16,777,216)
//   WaT   @ 16777216  : 3072x1024 bf16           ( 6,291,456)
//   WpT   @ 23068672  : 1024x1024 bf16           ( 2,097,152)
//   Q     @ 25165824  : [64][2048][64] bf16      (pre-scaled by log2e/8)
//   K     @ 41943040  : [64][2048][64] bf16
//   Vt    @ 58720256  : [64][64][2048] bf16      (V transposed per head)
//   Y     @ 75497472  : 8192x1024 bf16
// ---------------------------------------------------------------------------

typedef __bf16 bf16_t;
typedef __bf16 bf16x8 __attribute__((ext_vector_type(8)));
typedef __bf16 bf16x4 __attribute__((ext_vector_type(4)));
typedef float  f32x4  __attribute__((ext_vector_type(4)));

#define MFMA16(a, b, c) __builtin_amdgcn_mfma_f32_16x16x32_bf16((a), (b), (c), 0, 0, 0)

static __device__ __forceinline__ void gld_lds16(const bf16_t* g, void* l) {
  __builtin_amdgcn_global_load_lds(
      (const __attribute__((address_space(1))) void*)(const void*)g,
      (__attribute__((address_space(3))) void*)l, 16, 0, 0);
}

static __device__ __forceinline__ bf16x8 ldv8(const void* p) {
  return *reinterpret_cast<const bf16x8*>(p);
}

static __device__ __forceinline__ float exp2_hw(float x) {
  float r;
  asm("v_exp_f32 %0, %1" : "=v"(r) : "v"(x));
  return r;
}

// ---------------------------------------------------------------- prep ----
__global__ __launch_bounds__(256) void cvt_f32_bf16(const float* __restrict__ in,
                                                    bf16_t* __restrict__ out, int n4) {
  int i = blockIdx.x * 256 + threadIdx.x;
  if (i < n4) {
    float4 v = reinterpret_cast<const float4*>(in)[i];
    bf16x4 o;
    o[0] = (bf16_t)v.x; o[1] = (bf16_t)v.y; o[2] = (bf16_t)v.z; o[3] = (bf16_t)v.w;
    reinterpret_cast<bf16x4*>(out)[i] = o;
  }
}

// in [Kd][Nd] f32  ->  out [Nd][Kd] bf16
__global__ __launch_bounds__(256) void transpose_cvt(const float* __restrict__ in,
                                                     bf16_t* __restrict__ out,
                                                     int Kd, int Nd) {
  __shared__ float tile[32][33];
  int tx = threadIdx.x, ty = threadIdx.y;
  int n0 = blockIdx.x * 32, k0 = blockIdx.y * 32;
#pragma unroll
  for (int i = 0; i < 4; ++i)
    tile[ty + i * 8][tx] = in[(size_t)(k0 + ty + i * 8) * Nd + (n0 + tx)];
  __syncthreads();
#pragma unroll
  for (int i = 0; i < 4; ++i)
    out[(size_t)(n0 + ty + i * 8) * Kd + (k0 + tx)] = (bf16_t)tile[tx][ty + i * 8];
}

// ---------------------------------------------------------------- GEMM ----
// 256x256 tile, BK=64, 8 waves (2M x 4N), per-wave output 128x64 (0.375
// ds_reads/MFMA). LDS 128KB = 2 bufs x (A 32K + B 32K) -> 1 block/CU =
// 2 waves/SIMD. __launch_bounds__(512, 2): VGPR cap 256/wave — r11 shipped
// this kernel WITHOUT the bound; allocator picked 116 VGPR and spilled acc
// to scratch (WRITE_SIZE 96MB vs 50MB real, MfmaUtil 17%). Live state is
// ~215 VGPR (acc 128 + frags 64 + addr) and MUST stay in registers.
// FOUR phases per K-tile (C-quadrants Q00,Q01,Q10,Q11): A-half/B-half frags
// each read ONCE, used TWICE. Each phase: {ds_read ; [P0/P1: stage kt+1] ;
// barrier ; lgkm(0) ; setprio(1) 16 MFMA setprio(0) ; [P3: vmcnt(0), staged
// ~3 phases earlier] ; barrier}. Source-side XOR swizzle (G21). XCD-chunked
// M-fastest order (L2-fit). MODE 0: scatter Q/K/Vt. MODE 1: f32 out.
template <int MODE>
__global__ __launch_bounds__(512, 2) void gemm256(
    const bf16_t* __restrict__ A, const bf16_t* __restrict__ Bt,
    const float* __restrict__ bias, int M, int N, int K,
    bf16_t* __restrict__ Qo, bf16_t* __restrict__ Ko, bf16_t* __restrict__ Vt,
    float* __restrict__ Co) {
  __shared__ alignas(16) char lds[131072];  // buf k: A @k*64K, B @k*64K+32K

  const int tid = threadIdx.x;
  const int wave = tid >> 6, lane = tid & 63;
  const int wm = wave >> 2, wn = wave & 3;   // 2M x 4N wave grid
  const int l16 = lane & 15, kb = lane >> 4;
  const int r7 = l16 & 7;

  // XCD-chunked, M-fastest tile order (requires nwg % 8 == 0)
  const int nbx = gridDim.x;
  const int lb = blockIdx.y * nbx + blockIdx.x;
  const int c = lb & 7;
  const int ii = lb >> 3;
  const int rPer = gridDim.y >> 3;
  const int tmt = c * rPer + (ii % rPer);
  const int tnt = ii / rPer;
  const int tm0 = tmt * 256, tn0 = tnt * 256;

  // staging: row = inst*64 + (tid>>3), chunk = tid&7, source-side swizzle
  const int srow = tid >> 3;
  const int sch = (tid & 7) ^ (srow & 7);
  const bf16_t* aR = A + (size_t)(tm0 + srow) * K + sch * 8;
  const bf16_t* bR = Bt + (size_t)(tn0 + srow) * K + sch * 8;

  auto stageA = [&](int buf, int kt) {       // 4 insts/wave (256 rows)
    char* d = lds + buf * 65536 + wave * 1024;
    const bf16_t* s = aR + kt * 64;
#pragma unroll
    for (int i = 0; i < 4; ++i)
      gld_lds16(s + (size_t)(i * 64) * K, d + i * 8192);
  };
  auto stageB = [&](int buf, int kt) {       // 4 insts/wave (256 rows)
    char* d = lds + buf * 65536 + 32768 + wave * 1024;
    const bf16_t* s = bR + kt * 64;
#pragma unroll
    for (int i = 0; i < 4; ++i)
      gld_lds16(s + (size_t)(i * 64) * K, d + i * 8192);
  };

  f32x4 acc[8][4] = {};
  const int NK = K >> 6;                     // 16

  stageA(0, 0); stageB(0, 0);
  asm volatile("s_waitcnt vmcnt(0)" ::: "memory");
  __builtin_amdgcn_s_barrier();
  __builtin_amdgcn_sched_barrier(0);

  for (int kt = 0; kt < NK; ++kt) {
    const int buf = kt & 1;
    const char* Ab = lds + buf * 65536;
    const char* Bb = Ab + 32768;
    const bool more = (kt + 1 < NK);
    const int arow = wm * 128 + l16;         // + mi*16 (row&7 == r7 always)
    const int brow = wn * 64 + l16;          // + ni*16

    bf16x8 af[4][2], b0[2][2], b1[2][2];

    // ---- P0: read A-half0 (8) + B-half0 (4); stage A(kt+1); MFMA Q00 ----
#pragma unroll
    for (int mi = 0; mi < 4; ++mi)
#pragma unroll
      for (int kc = 0; kc < 2; ++kc)
        af[mi][kc] = ldv8(Ab + (arow + mi * 16) * 128 + (((kc * 4 + kb) ^ r7) * 16));
#pragma unroll
    for (int ni = 0; ni < 2; ++ni)
#pragma unroll
      for (int kc = 0; kc < 2; ++kc)
        b0[ni][kc] = ldv8(Bb + (brow + ni * 16) * 128 + (((kc * 4 + kb) ^ r7) * 16));
    if (more) stageA(buf ^ 1, kt + 1);
    __builtin_amdgcn_s_barrier();
    asm volatile("s_waitcnt lgkmcnt(0)" ::: "memory");
    __builtin_amdgcn_sched_barrier(0);
    __builtin_amdgcn_s_setprio(1);
#pragma unroll
    for (int mi = 0; mi < 4; ++mi)
#pragma unroll
      for (int ni = 0; ni < 2; ++ni)
#pragma unroll
        for (int kc = 0; kc < 2; ++kc)
          acc[mi][ni] = MFMA16(af[mi][kc], b0[ni][kc], acc[mi][ni]);
    __builtin_amdgcn_s_setprio(0);
    __builtin_amdgcn_s_barrier();

    // ---- P1: read B-half1 (4); stage B(kt+1); MFMA Q01 (reuse A0) ----
#pragma unroll
    for (int ni = 0; ni < 2; ++ni)
#pragma unroll
      for (int kc = 0; kc < 2; ++kc)
        b1[ni][kc] = ldv8(Bb + (brow + (2 + ni) * 16) * 128 + (((kc * 4 + kb) ^ r7) * 16));
    if (more) stageB(buf ^ 1, kt + 1);
    __builtin_amdgcn_s_barrier();
    asm volatile("s_waitcnt lgkmcnt(0)" ::: "memory");
    __builtin_amdgcn_sched_barrier(0);
    __builtin_amdgcn_s_setprio(1);
#pragma unroll
    for (int mi = 0; mi < 4; ++mi)
#pragma unroll
      for (int ni = 0; ni < 2; ++ni)
#pragma unroll
        for (int kc = 0; kc < 2; ++kc)
          acc[mi][2 + ni] = MFMA16(af[mi][kc], b1[ni][kc], acc[mi][2 + ni]);
    __builtin_amdgcn_s_setprio(0);
    __builtin_amdgcn_s_barrier();

    // ---- P2: read A-half1 (8, overwrite af); MFMA Q10 (reuse B0) ----
#pragma unroll
    for (int mi = 0; mi < 4; ++mi)
#pragma unroll
      for (int kc = 0; kc < 2; ++kc)
        af[mi][kc] = ldv8(Ab + (arow + (4 + mi) * 16) * 128 + (((kc * 4 + kb) ^ r7) * 16));
    __builtin_amdgcn_s_barrier();
    asm volatile("s_waitcnt lgkmcnt(0)" ::: "memory");
    __builtin_amdgcn_sched_barrier(0);
    __builtin_amdgcn_s_setprio(1);
#pragma unroll
    for (int mi = 0; mi < 4; ++mi)
#pragma unroll
      for (int ni = 0; ni < 2; ++ni)
#pragma unroll
        for (int kc = 0; kc < 2; ++kc)
          acc[4 + mi][ni] = MFMA16(af[mi][kc], b0[ni][kc], acc[4 + mi][ni]);
    __builtin_amdgcn_s_setprio(0);
    __builtin_amdgcn_s_barrier();

    // ---- P3: no reads; MFMA Q11; vmcnt(0) (staged ~3 phases ago) ----
    __builtin_amdgcn_s_setprio(1);
#pragma unroll
    for (int mi = 0; mi < 4; ++mi)
#pragma unroll
      for (int ni = 0; ni < 2; ++ni)
#pragma unroll
        for (int kc = 0; kc < 2; ++kc)
          acc[4 + mi][2 + ni] = MFMA16(af[mi][kc], b1[ni][kc], acc[4 + mi][2 + ni]);
    __builtin_amdgcn_s_setprio(0);
    if (more) asm volatile("s_waitcnt vmcnt(0)" ::: "memory");
    __builtin_amdgcn_s_barrier();
    __builtin_amdgcn_sched_barrier(0);
  }

  // epilogue: C/D layout col=lane&15, row=(lane>>4)*4+j  [verified m89]
#pragma unroll
  for (int ni = 0; ni < 4; ++ni) {
    const int n = tn0 + wn * 64 + ni * 16 + l16;
    const float bv = bias[n];
#pragma unroll
    for (int mi = 0; mi < 8; ++mi) {
#pragma unroll
      for (int j = 0; j < 4; ++j) {
        const int m = tm0 + wm * 128 + mi * 16 + kb * 4 + j;
        const float v = acc[mi][ni][j] + bv;
        if constexpr (MODE == 0) {
          const int which = n >> 10, hn = n & 1023;
          const int h = hn >> 6, d = hn & 63;
          const int b = m >> 11, t = m & 2047;
          const size_t bh = (size_t)(b * 16 + h);
          if (which == 0)  // fold 1/sqrt(hs) * log2(e) for base-2 softmax
            Qo[(bh * 2048 + t) * 64 + d] = (bf16_t)(v * 0.18033688011112042f);
          else if (which == 1)
            Ko[(bh * 2048 + t) * 64 + d] = (bf16_t)v;
          else
            Vt[(bh * 64 + d) * 2048 + t] = (bf16_t)v;
        } else {
          Co[(size_t)m * N + n] = v;
        }
      }
    }
  }
}

// ----------------------------------------------------------- attention ----
// (unchanged from round 9/10)
// Single q-tile per block (64 rows, 4 waves x 16), 2048 blocks, LPT order.
// Swapped-QK: lane owns one q-row. LDS 40KB -> 4 blocks/CU + backfill.
// Defer-max base-2 softmax, diagonal-only masking, partial l_r.
__global__ __launch_bounds__(256) void attn_fwd(const bf16_t* __restrict__ Qg,
                                                const bf16_t* __restrict__ Kg,
                                                const bf16_t* __restrict__ Vtg,
                                                bf16_t* __restrict__ Yg) {
  __shared__ alignas(16) char lds[40960];  // K 2x8K @0, V 2x8K @16384, P 8K @32768

  const int tid = threadIdx.x;
  const int wave = tid >> 6, lane = tid & 63;
  const int l16 = lane & 15, kb = lane >> 4;
  const int l8 = l16 & 7;
  const float NEG_INF = -__builtin_inff();

  const int n = blockIdx.x;                    // 2048 blocks
  const int bh = (n & 7) * 8 + ((n >> 3) & 7); // 8 heads per XCD
  const int qt = 31 - (n >> 6);                // longest-first (LPT)
  const size_t base = (size_t)bh * (2048 * 64);
  const int b = bh >> 4, h = bh & 15;

  const int srow = tid >> 3;
  const int schunk = (tid & 7) ^ (srow & 7);
  const bf16_t* Ksrc = Kg + base + (size_t)srow * 64 + schunk * 8;
  const bf16_t* Vsrc = Vtg + base + (size_t)srow * 2048 + schunk * 8;

  auto stageK = [&](int buf, int kv0) {
    char* kd = lds + buf * 8192 + wave * 1024;
    const bf16_t* ks = Ksrc + (size_t)kv0 * 64;
    gld_lds16(ks, kd);
    gld_lds16(ks + 2048, kd + 4096);
  };
  auto stageV = [&](int buf, int kv0) {
    char* vd = lds + 16384 + buf * 8192 + wave * 1024;
    const bf16_t* vs = Vsrc + kv0;
    gld_lds16(vs, vd);
    gld_lds16(vs + 65536, vd + 4096);
  };

  const int q0 = qt * 64 + wave * 16;
  const int q = q0 + l16;                      // this lane's q-row
  const int trips = qt + 1;

  const bf16x8 qf0 = ldv8(Qg + base + (size_t)q * 64 + kb * 8);
  const bf16x8 qf1 = ldv8(Qg + base + (size_t)q * 64 + 32 + kb * 8);

  f32x4 o[4] = {};
  float m_r = NEG_INF, l_r = 0.f;

  char* Pw = lds + 32768 + wave * 2048;

  stageK(0, 0);
  stageV(0, 0);
  asm volatile("s_waitcnt vmcnt(0)" ::: "memory");
  __builtin_amdgcn_s_barrier();
  __builtin_amdgcn_sched_barrier(0);

  int cur = 0;
  for (int t = 0; t < trips; ++t) {
    const int kv0 = t * 64;
    const bool more = (t + 1 < trips);
    if (more) {
      stageK(cur ^ 1, kv0 + 64);               // async, drains at iter end
      stageV(cur ^ 1, kv0 + 64);
    }

    const char* Kb = lds + cur * 8192;
    const char* Vb = lds + 16384 + cur * 8192;

    bf16x8 kf[8];
#pragma unroll
    for (int i = 0; i < 4; ++i) {
      const int row = i * 16 + l16;
#pragma unroll
      for (int kc = 0; kc < 2; ++kc)
        kf[i * 2 + kc] = ldv8(Kb + row * 128 + (((kc * 4 + kb) ^ (row & 7)) * 16));
    }

    f32x4 s[4] = {};
    __builtin_amdgcn_s_setprio(1);
#pragma unroll
    for (int i = 0; i < 4; ++i) {
      s[i] = MFMA16(kf[i * 2 + 0], qf0, s[i]);
      s[i] = MFMA16(kf[i * 2 + 1], qf1, s[i]);
    }
    __builtin_amdgcn_s_setprio(0);

    bf16x8 vf[8];
#pragma unroll
    for (int i = 0; i < 4; ++i) {
      const int row = i * 16 + l16;
#pragma unroll
      for (int kc = 0; kc < 2; ++kc)
        vf[i * 2 + kc] = ldv8(Vb + row * 128 + (((kc * 4 + kb) ^ (row & 7)) * 16));
    }

    // --- online softmax, base-2, defer-max, partial l ------------------
    float pm[4];
    if (t == qt) {  // diagonal tile: causal mask (wave-uniform branch)
#pragma unroll
      for (int i = 0; i < 4; ++i) {
        f32x4 sv = s[i];
#pragma unroll
        for (int j = 0; j < 4; ++j)
          if (kv0 + i * 16 + kb * 4 + j > q) sv[j] = NEG_INF;
        s[i] = sv;
        pm[i] = fmaxf(fmaxf(sv[0], sv[1]), fmaxf(sv[2], sv[3]));
      }
    } else {
#pragma unroll
      for (int i = 0; i < 4; ++i)
        pm[i] = fmaxf(fmaxf(s[i][0], s[i][1]), fmaxf(s[i][2], s[i][3]));
    }
    float mx = fmaxf(fmaxf(pm[0], pm[1]), fmaxf(pm[2], pm[3]));
    if (__any(mx > m_r + 8.0f)) {              // rare: full reduce + rescale
      mx = fmaxf(mx, __shfl_xor(mx, 16));
      mx = fmaxf(mx, __shfl_xor(mx, 32));
      const float mn = fmaxf(m_r, mx);
      const float sc = exp2_hw(m_r - mn);
      l_r *= sc;
#pragma unroll
      for (int i = 0; i < 4; ++i) {
        o[i][0] *= sc; o[i][1] *= sc; o[i][2] *= sc; o[i][3] *= sc;
      }
      m_r = mn;
    }
    float ss = 0.f;
    bf16x4 pw[4];
#pragma unroll
    for (int i = 0; i < 4; ++i)
#pragma unroll
      for (int j = 0; j < 4; ++j) {
        const float p = exp2_hw(s[i][j] - m_r);
        ss += p;
        pw[i][j] = (bf16_t)p;
      }
    l_r += ss;                                  // partial; reduced in epilogue

    // P^T roundtrip, wave-private (16B-chunk XOR swizzle; verified r3-r11)
#pragma unroll
    for (int i = 0; i < 4; ++i) {
      const int phys = (i * 2 + (kb >> 1)) ^ l8;
      *reinterpret_cast<bf16x4*>(Pw + l16 * 128 + phys * 16 + (kb & 1) * 8) = pw[i];
    }
    const bf16x8 pb0 = ldv8(Pw + l16 * 128 + ((kb ^ l8) * 16));
    const bf16x8 pb1 = ldv8(Pw + l16 * 128 + (((4 + kb) ^ l8) * 16));

    __builtin_amdgcn_s_setprio(1);
#pragma unroll
    for (int i = 0; i < 4; ++i) {
      o[i] = MFMA16(vf[i * 2 + 0], pb0, o[i]);
      o[i] = MFMA16(vf[i * 2 + 1], pb1, o[i]);
    }
    __builtin_amdgcn_s_setprio(0);

    asm volatile("s_waitcnt vmcnt(0)" ::: "memory");
    __builtin_amdgcn_s_barrier();
    __builtin_amdgcn_sched_barrier(0);
    cur ^= 1;
  }

  float lt = l_r + __shfl_xor(l_r, 16);
  lt += __shfl_xor(lt, 32);
  const float inv = 1.0f / lt;
  bf16_t* yrow = Yg + ((size_t)(b * 2048 + q)) * 1024 + h * 64;
#pragma unroll
  for (int i = 0; i < 4; ++i) {
    bf16x4 yv;
    yv[0] = (bf16_t)(o[i][0] * inv);
    yv[1] = (bf16_t)(o[i][1] * inv);
    yv[2] = (bf16_t)(o[i][2] * inv);
    yv[3] = (bf16_t)(o[i][3] * inv);
    *reinterpret_cast<bf16x4*>(yrow + i * 16 + kb * 4) = yv;
  }
}

// --------------------------------------------------------------- launch ---
extern "C" void kernel_launch(void* const* d_in, const int* in_sizes, int n_in,
                              void* d_out, int out_size, void* d_ws, size_t ws_size,
                              hipStream_t stream) {
  const float* x = (const float*)d_in[0];
  const float* W_attn = (const float*)d_in[1];
  const float* b_attn = (const float*)d_in[2];
  const float* W_proj = (const float*)d_in[3];
  const float* b_proj = (const float*)d_in[4];
  float* out = (float*)d_out;

  char* ws = (char*)d_ws;
  bf16_t* xb  = (bf16_t*)(ws + 0);
  bf16_t* WaT = (bf16_t*)(ws + 16777216);
  bf16_t* WpT = (bf16_t*)(ws + 23068672);
  bf16_t* Qb  = (bf16_t*)(ws + 25165824);
  bf16_t* Kb  = (bf16_t*)(ws + 41943040);
  bf16_t* Vt  = (bf16_t*)(ws + 58720256);
  bf16_t* Yb  = (bf16_t*)(ws + 75497472);

  cvt_f32_bf16<<<8192, 256, 0, stream>>>(x, xb, 8192 * 1024 / 4);
  transpose_cvt<<<dim3(96, 32), dim3(32, 8), 0, stream>>>(W_attn, WaT, 1024, 3072);
  transpose_cvt<<<dim3(32, 32), dim3(32, 8), 0, stream>>>(W_proj, WpT, 1024, 1024);

  // qkv: M=8192 (32 tiles of 256), N=3072 (12 tiles of 256) -> 384 blocks
  gemm256<0><<<dim3(12, 32), 512, 0, stream>>>(xb, WaT, b_attn, 8192, 3072, 1024,
                                               Qb, Kb, Vt, nullptr);

  attn_fwd<<<2048, 256, 0, stream>>>(Qb, Kb, Vt, Yb);

  // proj: M=8192, N=1024 (4 tiles of 256) -> 128 blocks
  gemm256<1><<<dim3(4, 32), 512, 0, stream>>>(Yb, WpT, b_proj, 8192, 1024, 1024,
                                              nullptr, nullptr, nullptr, out);
}

// Round 13
// 183.869 us; speedup vs baseline: 1.1413x; 1.1413x over previous
//
#include <hip/hip_runtime.h>

// ---------------------------------------------------------------------------
// CausalSelfAttention forward on MI355X (gfx950).
// B=4, T=2048, C=1024, H=16, hs=64.
// Pipeline: [cvt x->bf16, transpose W's] -> QKV GEMM (128x128, M-fastest XCD
//           chunks; r9-verified best) -> flash attention (swapped-QK, single
//           q-tile/block, LPT, 24KB LDS w/ P-in-dead-K) -> proj GEMM.
// Workspace layout (bytes):
//   xb    @ 0         : 8192x1024 bf16           (16,777,216)
//   WaT   @ 16777216  : 3072x1024 bf16           ( 6,291,456)
//   WpT   @ 23068672  : 1024x1024 bf16           ( 2,097,152)
//   Q     @ 25165824  : [64][2048][64] bf16      (pre-scaled by log2e/8)
//   K     @ 41943040  : [64][2048][64] bf16
//   Vt    @ 58720256  : [64][64][2048] bf16      (V transposed per head)
//   Y     @ 75497472  : 8192x1024 bf16
// ---------------------------------------------------------------------------

typedef __bf16 bf16_t;
typedef __bf16 bf16x8 __attribute__((ext_vector_type(8)));
typedef __bf16 bf16x4 __attribute__((ext_vector_type(4)));
typedef float  f32x4  __attribute__((ext_vector_type(4)));

#define MFMA16(a, b, c) __builtin_amdgcn_mfma_f32_16x16x32_bf16((a), (b), (c), 0, 0, 0)

static __device__ __forceinline__ void gld_lds16(const bf16_t* g, void* l) {
  __builtin_amdgcn_global_load_lds(
      (const __attribute__((address_space(1))) void*)(const void*)g,
      (__attribute__((address_space(3))) void*)l, 16, 0, 0);
}

static __device__ __forceinline__ bf16x8 ldv8(const void* p) {
  return *reinterpret_cast<const bf16x8*>(p);
}

static __device__ __forceinline__ float exp2_hw(float x) {
  float r;
  asm("v_exp_f32 %0, %1" : "=v"(r) : "v"(x));
  return r;
}

// ---------------------------------------------------------------- prep ----
__global__ __launch_bounds__(256) void cvt_f32_bf16(const float* __restrict__ in,
                                                    bf16_t* __restrict__ out, int n4) {
  int i = blockIdx.x * 256 + threadIdx.x;
  if (i < n4) {
    float4 v = reinterpret_cast<const float4*>(in)[i];
    bf16x4 o;
    o[0] = (bf16_t)v.x; o[1] = (bf16_t)v.y; o[2] = (bf16_t)v.z; o[3] = (bf16_t)v.w;
    reinterpret_cast<bf16x4*>(out)[i] = o;
  }
}

// in [Kd][Nd] f32  ->  out [Nd][Kd] bf16
__global__ __launch_bounds__(256) void transpose_cvt(const float* __restrict__ in,
                                                     bf16_t* __restrict__ out,
                                                     int Kd, int Nd) {
  __shared__ float tile[32][33];
  int tx = threadIdx.x, ty = threadIdx.y;
  int n0 = blockIdx.x * 32, k0 = blockIdx.y * 32;
#pragma unroll
  for (int i = 0; i < 4; ++i)
    tile[ty + i * 8][tx] = in[(size_t)(k0 + ty + i * 8) * Nd + (n0 + tx)];
  __syncthreads();
#pragma unroll
  for (int i = 0; i < 4; ++i)
    out[(size_t)(n0 + ty + i * 8) * Kd + (k0 + tx)] = (bf16_t)tile[tx][ty + i * 8];
}

// ---------------------------------------------------------------- GEMM ----
// (r9-verified: 128x128 tile, BK=64, 4 waves, gld_lds staging w/ source-side
// XOR swizzle, XCD-chunked M-fastest tile order. Best measured: 84 us QKV.)
// MODE 0: scatter qkv -> Q (x log2e/8), K, Vt. MODE 1: f32 out.
template <int MODE>
__global__ __launch_bounds__(256) void gemm_bf16(
    const bf16_t* __restrict__ A, const bf16_t* __restrict__ Bt,
    const float* __restrict__ bias, int M, int N, int K,
    bf16_t* __restrict__ Qo, bf16_t* __restrict__ Ko, bf16_t* __restrict__ Vt,
    float* __restrict__ Co) {
  __shared__ alignas(16) char lds[32768];

  const int tid = threadIdx.x;
  const int wave = tid >> 6, lane = tid & 63;
  const int wm = wave >> 1, wn = wave & 1;
  const int l16 = lane & 15, kb = lane >> 4;

  // XCD-chunked, M-fastest tile order (requires gridDim.y % 8 == 0)
  const int nbx = gridDim.x;
  const int lb = blockIdx.y * nbx + blockIdx.x;
  const int c = lb & 7;
  const int ii = lb >> 3;
  const int rPer = gridDim.y >> 3;
  const int tmt = c * rPer + (ii % rPer);
  const int tnt = ii / rPer;
  const int tm0 = tmt * 128, tn0 = tnt * 128;

  const int srow = wave * 8 + (lane >> 3);
  const int sp = lane & 7;

  f32x4 acc[4][4] = {};

  for (int k0 = 0; k0 < K; k0 += 64) {
    __syncthreads();
#pragma unroll
    for (int inst = 0; inst < 4; ++inst) {
      const int row = inst * 32 + srow;
      const int chunk = (sp ^ (row & 7)) * 8;
      gld_lds16(A + (size_t)(tm0 + row) * K + k0 + chunk,
                &lds[inst * 4096 + wave * 1024]);
      gld_lds16(Bt + (size_t)(tn0 + row) * K + k0 + chunk,
                &lds[16384 + inst * 4096 + wave * 1024]);
    }
    __syncthreads();
#pragma unroll
    for (int kc = 0; kc < 2; ++kc) {
      bf16x8 af[4], bfr[4];
#pragma unroll
      for (int mi = 0; mi < 4; ++mi) {
        const int row = wm * 64 + mi * 16 + l16;
        const int slot = (kc * 4 + kb) ^ (row & 7);
        af[mi] = ldv8(&lds[row * 128 + slot * 16]);
      }
#pragma unroll
      for (int ni = 0; ni < 4; ++ni) {
        const int row = wn * 64 + ni * 16 + l16;
        const int slot = (kc * 4 + kb) ^ (row & 7);
        bfr[ni] = ldv8(&lds[16384 + row * 128 + slot * 16]);
      }
#pragma unroll
      for (int mi = 0; mi < 4; ++mi)
#pragma unroll
        for (int ni = 0; ni < 4; ++ni)
          acc[mi][ni] = MFMA16(af[mi], bfr[ni], acc[mi][ni]);
    }
  }

#pragma unroll
  for (int ni = 0; ni < 4; ++ni) {
    const int n = tn0 + wn * 64 + ni * 16 + l16;
    const float bv = bias[n];
#pragma unroll
    for (int mi = 0; mi < 4; ++mi) {
#pragma unroll
      for (int j = 0; j < 4; ++j) {
        const int m = tm0 + wm * 64 + mi * 16 + kb * 4 + j;
        const float v = acc[mi][ni][j] + bv;
        if constexpr (MODE == 0) {
          const int which = n >> 10, hn = n & 1023;
          const int h = hn >> 6, d = hn & 63;
          const int b = m >> 11, t = m & 2047;
          const size_t bh = (size_t)(b * 16 + h);
          if (which == 0)  // fold 1/sqrt(hs) * log2(e) for base-2 softmax
            Qo[(bh * 2048 + t) * 64 + d] = (bf16_t)(v * 0.18033688011112042f);
          else if (which == 1)
            Ko[(bh * 2048 + t) * 64 + d] = (bf16_t)v;
          else
            Vt[(bh * 64 + d) * 2048 + t] = (bf16_t)v;
        } else {
          Co[(size_t)m * N + n] = v;
        }
      }
    }
  }
}

// ----------------------------------------------------------- attention ----
// r9 structure (single q-tile/block, 64 rows, 4 waves x 16, 2048 blocks,
// LPT order, swapped-QK, defer-max base-2 softmax, partial l_r) with the
// r4-verified LDS diet: 24KB total. K dbuf 2x8K @0/@8192; V SINGLE 8K
// @16384, restaged after a mid-iteration lgkm-only barrier; P^T roundtrip
// reuses the DEAD K[cur] region (K[cur] fully in kf regs before the mid
// barrier; cross-wave safety from that barrier). End-of-iter vmcnt(0)
// drains both K-prefetch and V-restage.
__global__ __launch_bounds__(256) void attn_fwd(const bf16_t* __restrict__ Qg,
                                                const bf16_t* __restrict__ Kg,
                                                const bf16_t* __restrict__ Vtg,
                                                bf16_t* __restrict__ Yg) {
  __shared__ alignas(16) char lds[24576];  // K 2x8K @0, V 8K @16384

  const int tid = threadIdx.x;
  const int wave = tid >> 6, lane = tid & 63;
  const int l16 = lane & 15, kb = lane >> 4;
  const int l8 = l16 & 7;
  const float NEG_INF = -__builtin_inff();

  const int n = blockIdx.x;                    // 2048 blocks
  const int bh = (n & 7) * 8 + ((n >> 3) & 7); // 8 heads per XCD
  const int qt = 31 - (n >> 6);                // longest-first (LPT)
  const size_t base = (size_t)bh * (2048 * 64);
  const int b = bh >> 4, h = bh & 15;

  const int srow = tid >> 3;
  const int schunk = (tid & 7) ^ (srow & 7);
  const bf16_t* Ksrc = Kg + base + (size_t)srow * 64 + schunk * 8;
  const bf16_t* Vsrc = Vtg + base + (size_t)srow * 2048 + schunk * 8;

  auto stageK = [&](int buf, int kv0) {
    char* kd = lds + buf * 8192 + wave * 1024;
    const bf16_t* ks = Ksrc + (size_t)kv0 * 64;
    gld_lds16(ks, kd);
    gld_lds16(ks + 2048, kd + 4096);
  };
  auto stageV = [&](int kv0) {
    char* vd = lds + 16384 + wave * 1024;
    const bf16_t* vs = Vsrc + kv0;
    gld_lds16(vs, vd);
    gld_lds16(vs + 65536, vd + 4096);
  };

  const int q0 = qt * 64 + wave * 16;
  const int q = q0 + l16;                      // this lane's q-row
  const int trips = qt + 1;

  const bf16x8 qf0 = ldv8(Qg + base + (size_t)q * 64 + kb * 8);
  const bf16x8 qf1 = ldv8(Qg + base + (size_t)q * 64 + 32 + kb * 8);

  f32x4 o[4] = {};
  float m_r = NEG_INF, l_r = 0.f;

  stageK(0, 0);
  stageV(0);
  asm volatile("s_waitcnt vmcnt(0)" ::: "memory");
  __builtin_amdgcn_s_barrier();
  __builtin_amdgcn_sched_barrier(0);

  int cur = 0;
  for (int t = 0; t < trips; ++t) {
    const int kv0 = t * 64;
    const bool more = (t + 1 < trips);
    if (more) stageK(cur ^ 1, kv0 + 64);       // async, drains at iter end

    const char* Kb = lds + cur * 8192;
    const char* Vb = lds + 16384;

    bf16x8 kf[8];
#pragma unroll
    for (int i = 0; i < 4; ++i) {
      const int row = i * 16 + l16;
#pragma unroll
      for (int kc = 0; kc < 2; ++kc)
        kf[i * 2 + kc] = ldv8(Kb + row * 128 + (((kc * 4 + kb) ^ (row & 7)) * 16));
    }

    f32x4 s[4] = {};
    __builtin_amdgcn_s_setprio(1);
#pragma unroll
    for (int i = 0; i < 4; ++i) {
      s[i] = MFMA16(kf[i * 2 + 0], qf0, s[i]);
      s[i] = MFMA16(kf[i * 2 + 1], qf1, s[i]);
    }
    __builtin_amdgcn_s_setprio(0);

    bf16x8 vf[8];
#pragma unroll
    for (int i = 0; i < 4; ++i) {
      const int row = i * 16 + l16;
#pragma unroll
      for (int kc = 0; kc < 2; ++kc)
        vf[i * 2 + kc] = ldv8(Vb + row * 128 + (((kc * 4 + kb) ^ (row & 7)) * 16));
    }

    // --- online softmax, base-2, defer-max, partial l ------------------
    float pm[4];
    if (t == qt) {  // diagonal tile: causal mask (wave-uniform branch)
#pragma unroll
      for (int i = 0; i < 4; ++i) {
        f32x4 sv = s[i];
#pragma unroll
        for (int j = 0; j < 4; ++j)
          if (kv0 + i * 16 + kb * 4 + j > q) sv[j] = NEG_INF;
        s[i] = sv;
        pm[i] = fmaxf(fmaxf(sv[0], sv[1]), fmaxf(sv[2], sv[3]));
      }
    } else {
#pragma unroll
      for (int i = 0; i < 4; ++i)
        pm[i] = fmaxf(fmaxf(s[i][0], s[i][1]), fmaxf(s[i][2], s[i][3]));
    }
    float mx = fmaxf(fmaxf(pm[0], pm[1]), fmaxf(pm[2], pm[3]));
    if (__any(mx > m_r + 8.0f)) {              // rare: full reduce + rescale
      mx = fmaxf(mx, __shfl_xor(mx, 16));
      mx = fmaxf(mx, __shfl_xor(mx, 32));
      const float mn = fmaxf(m_r, mx);
      const float sc = exp2_hw(m_r - mn);
      l_r *= sc;
#pragma unroll
      for (int i = 0; i < 4; ++i) {
        o[i][0] *= sc; o[i][1] *= sc; o[i][2] *= sc; o[i][3] *= sc;
      }
      m_r = mn;
    }
    float ss = 0.f;
    bf16x4 pw[4];
#pragma unroll
    for (int i = 0; i < 4; ++i)
#pragma unroll
      for (int j = 0; j < 4; ++j) {
        const float p = exp2_hw(s[i][j] - m_r);
        ss += p;
        pw[i][j] = (bf16_t)p;
      }
    l_r += ss;                                  // partial; reduced in epilogue

    // --- mid-iter barrier: lgkm-only (vmcnt K-prefetch stays in flight) --
    // Guarantees: all waves' kf/vf ds_reads complete -> K[cur] dead (P may
    // alias it) and V consumable (restage may overwrite it).
    asm volatile("s_waitcnt lgkmcnt(0)" ::: "memory");
    __builtin_amdgcn_s_barrier();
    __builtin_amdgcn_sched_barrier(0);
    if (more) stageV(kv0 + 64);                // V restage, drains at iter end

    // P^T roundtrip through dead K[cur] (wave-private 2KB slice)
    char* Pw = lds + cur * 8192 + wave * 2048;
#pragma unroll
    for (int i = 0; i < 4; ++i) {
      const int phys = (i * 2 + (kb >> 1)) ^ l8;
      *reinterpret_cast<bf16x4*>(Pw + l16 * 128 + phys * 16 + (kb & 1) * 8) = pw[i];
    }
    const bf16x8 pb0 = ldv8(Pw + l16 * 128 + ((kb ^ l8) * 16));
    const bf16x8 pb1 = ldv8(Pw + l16 * 128 + (((4 + kb) ^ l8) * 16));

    __builtin_amdgcn_s_setprio(1);
#pragma unroll
    for (int i = 0; i < 4; ++i) {
      o[i] = MFMA16(vf[i * 2 + 0], pb0, o[i]);
      o[i] = MFMA16(vf[i * 2 + 1], pb1, o[i]);
    }
    __builtin_amdgcn_s_setprio(0);

    asm volatile("s_waitcnt vmcnt(0)" ::: "memory");
    __builtin_amdgcn_s_barrier();
    __builtin_amdgcn_sched_barrier(0);
    cur ^= 1;
  }

  float lt = l_r + __shfl_xor(l_r, 16);
  lt += __shfl_xor(lt, 32);
  const float inv = 1.0f / lt;
  bf16_t* yrow = Yg + ((size_t)(b * 2048 + q)) * 1024 + h * 64;
#pragma unroll
  for (int i = 0; i < 4; ++i) {
    bf16x4 yv;
    yv[0] = (bf16_t)(o[i][0] * inv);
    yv[1] = (bf16_t)(o[i][1] * inv);
    yv[2] = (bf16_t)(o[i][2] * inv);
    yv[3] = (bf16_t)(o[i][3] * inv);
    *reinterpret_cast<bf16x4*>(yrow + i * 16 + kb * 4) = yv;
  }
}

// --------------------------------------------------------------- launch ---
extern "C" void kernel_launch(void* const* d_in, const int* in_sizes, int n_in,
                              void* d_out, int out_size, void* d_ws, size_t ws_size,
                              hipStream_t stream) {
  const float* x = (const float*)d_in[0];
  const float* W_attn = (const float*)d_in[1];
  const float* b_attn = (const float*)d_in[2];
  const float* W_proj = (const float*)d_in[3];
  const float* b_proj = (const float*)d_in[4];
  float* out = (float*)d_out;

  char* ws = (char*)d_ws;
  bf16_t* xb  = (bf16_t*)(ws + 0);
  bf16_t* WaT = (bf16_t*)(ws + 16777216);
  bf16_t* WpT = (bf16_t*)(ws + 23068672);
  bf16_t* Qb  = (bf16_t*)(ws + 25165824);
  bf16_t* Kb  = (bf16_t*)(ws + 41943040);
  bf16_t* Vt  = (bf16_t*)(ws + 58720256);
  bf16_t* Yb  = (bf16_t*)(ws + 75497472);

  cvt_f32_bf16<<<8192, 256, 0, stream>>>(x, xb, 8192 * 1024 / 4);
  transpose_cvt<<<dim3(96, 32), dim3(32, 8), 0, stream>>>(W_attn, WaT, 1024, 3072);
  transpose_cvt<<<dim3(32, 32), dim3(32, 8), 0, stream>>>(W_proj, WpT, 1024, 1024);

  // qkv: M=8192, N=3072 -> grid 24x64 = 1536 blocks
  gemm_bf16<0><<<dim3(24, 64), 256, 0, stream>>>(xb, WaT, b_attn, 8192, 3072, 1024,
                                                 Qb, Kb, Vt, nullptr);

  attn_fwd<<<2048, 256, 0, stream>>>(Qb, Kb, Vt, Yb);

  // proj: M=8192, N=1024 -> grid 8x64 = 512 blocks
  gemm_bf16<1><<<dim3(8, 64), 256, 0, stream>>>(Yb, WpT, b_proj, 8192, 1024, 1024,
                                                nullptr, nullptr, nullptr, out);
}